// Round 10
// baseline (382.592 us; speedup 1.0000x reference)
//
#include <hip/hip_runtime.h>
#include <hip/hip_bf16.h>
#include <math.h>
#include <stdint.h>

#define B_ 4
#define S_ 1024
#define D_ 512
#define NH_ 8
#define DH_ 64
#define L_ 2
#define PRED_ 96
#define COUT_ 512

typedef __attribute__((ext_vector_type(8))) short short8;
typedef __attribute__((ext_vector_type(4))) float f32x4;

__device__ __forceinline__ unsigned short f2bf(float f) {
  union { float f; unsigned int u; } v; v.f = f;
  unsigned int r = v.u + 0x7fffu + ((v.u >> 16) & 1u);
  return (unsigned short)(r >> 16);
}
__device__ __forceinline__ float bf2f(unsigned short h) {
  union { unsigned int u; float f; } v; v.u = (unsigned int)h << 16;
  return v.f;
}

// ---------------- x_enc f32 [B,S,512] -> hi/lo bf16 [B*NH, S, 64] ----------------
__global__ __launch_bounds__(64) void convkv_kernel(
    const float* __restrict__ x, unsigned short* __restrict__ hiA,
    unsigned short* __restrict__ loA) {
  int bs = blockIdx.x;
  int b = bs >> 10, s = bs & 1023;
  int t = threadIdx.x;
  int h = t >> 3, dh0 = (t & 7) * 8;
  const float* src = x + (size_t)bs * D_ + t * 8;
  float4 v0 = *(const float4*)(src);
  float4 v1 = *(const float4*)(src + 4);
  float xv[8] = {v0.x, v0.y, v0.z, v0.w, v1.x, v1.y, v1.z, v1.w};
  unsigned short hh[8], ll[8];
#pragma unroll
  for (int k = 0; k < 8; ++k) {
    hh[k] = f2bf(xv[k]);
    ll[k] = f2bf(xv[k] - bf2f(hh[k]));
  }
  size_t off = (((size_t)(b * NH_ + h)) * S_ + s) * 64 + dh0;
  *(uint4*)(hiA + off) = *(const uint4*)hh;
  *(uint4*)(loA + off) = *(const uint4*)ll;
}

// ---------------- [B*NH,S,64] -> [B*NH,64,S] ----------------
__global__ __launch_bounds__(256) void transpose_kernel(
    const unsigned short* __restrict__ src_a, unsigned short* __restrict__ dst_a) {
  int jt = blockIdx.x, h = blockIdx.y, b = blockIdx.z;
  int bh = b * NH_ + h, j0 = jt * 64;
  __shared__ unsigned short tile[64][72];
  int t = threadIdx.x;
  {
    int j = t >> 2, dseg = (t & 3) * 16;
    const unsigned short* src = src_a + ((size_t)bh * S_ + j0 + j) * 64 + dseg;
    uint4 a0 = *(const uint4*)(src);
    uint4 a1 = *(const uint4*)(src + 8);
    *(uint4*)(&tile[j][dseg]) = a0;
    *(uint4*)(&tile[j][dseg + 8]) = a1;
  }
  __syncthreads();
  {
    int d = t >> 2, jseg = (t & 3) * 16;
    unsigned short us[16];
#pragma unroll
    for (int k = 0; k < 16; ++k) us[k] = tile[jseg + k][d];
    unsigned short* dst = dst_a + ((size_t)bh * 64 + d) * S_ + j0 + jseg;
    *(uint4*)(dst) = *(const uint4*)us;
    *(uint4*)(dst + 8) = *(const uint4*)(us + 8);
  }
}

// ---------------- gates ----------------
__global__ __launch_bounds__(256) void gates2_kernel(
    const float* __restrict__ q, const float* __restrict__ x,
    const float* __restrict__ Wig, const float* __restrict__ big,
    const float* __restrict__ Wfg, const float* __restrict__ bfg,
    float* __restrict__ ig_out, float* __restrict__ fg_out) {
  int sc = blockIdx.x, hg = blockIdx.y, b = blockIdx.z;
  __shared__ float Wq_s[8][512];
  __shared__ float Wc_s[8][512];
  for (int idx = threadIdx.x; idx < 8 * 512; idx += 256) {
    int p = idx >> 9, e = idx & 511;
    int h = hg * 4 + (p >> 1);
    const float* Wr = ((p & 1) ? Wfg : Wig) + (size_t)h * (3 * D_);
    Wq_s[p][e] = Wr[e];
    Wc_s[p][e] = Wr[512 + e] + Wr[1024 + e];
  }
  __syncthreads();
  int wv = threadIdx.x >> 6, l = threadIdx.x & 63;
  for (int rr = 0; rr < 8; ++rr) {
    int s = sc * 32 + wv * 8 + rr;
    const float* qrow = q + ((size_t)(b * S_ + s)) * D_;
    const float* xrow = x + ((size_t)(b * S_ + s)) * D_;
    float ql[8], xl[8];
#pragma unroll
    for (int k = 0; k < 8; ++k) { ql[k] = qrow[l + 64 * k]; xl[k] = xrow[l + 64 * k]; }
#pragma unroll
    for (int p = 0; p < 8; ++p) {
      float acc = 0.f;
#pragma unroll
      for (int k = 0; k < 8; ++k)
        acc += Wq_s[p][l + 64 * k] * ql[k] + Wc_s[p][l + 64 * k] * xl[k];
#pragma unroll
      for (int off = 32; off; off >>= 1) acc += __shfl_down(acc, off);
      if (l == 0) {
        int h = hg * 4 + (p >> 1);
        float v = acc + ((p & 1) ? bfg : big)[h];
        ((p & 1) ? fg_out : ig_out)[((size_t)(b * NH_ + h)) * S_ + s] = v;
      }
    }
  }
}

// ---------------- scan: a = ig - cumsum(logsig(fg)); amax = cummax(a) ----------------
__global__ __launch_bounds__(64) void scan_kernel(
    const float* __restrict__ ig, const float* __restrict__ fg,
    float* __restrict__ a_out, float* __restrict__ amax_out) {
  int bh = blockIdx.x;
  int lane = threadIdx.x;
  const float* igr = ig + (size_t)bh * S_;
  const float* fgr = fg + (size_t)bh * S_;
  const int CH = S_ / 64;
  float lf[16], av[16];
  float lsum = 0.f;
  int base = lane * CH;
  for (int u = 0; u < CH; ++u) {
    float xv = fgr[base + u];
    float ls = (xv >= 0.f) ? -log1pf(__expf(-xv)) : (xv - log1pf(__expf(xv)));
    lf[u] = ls; lsum += ls;
  }
  float pref = lsum;
#pragma unroll
  for (int off = 1; off < 64; off <<= 1) {
    float t = __shfl_up(pref, off);
    if (lane >= off) pref += t;
  }
  float F = pref - lsum;
  float lamax = -INFINITY;
  for (int u = 0; u < CH; ++u) {
    F += lf[u];
    float a = igr[base + u] - F;
    av[u] = a;
    lamax = fmaxf(lamax, a);
  }
  float pmax = lamax;
#pragma unroll
  for (int off = 1; off < 64; off <<= 1) {
    float t = __shfl_up(pmax, off);
    if (lane >= off) pmax = fmaxf(pmax, t);
  }
  float run = __shfl_up(pmax, 1);
  if (lane == 0) run = -INFINITY;
  for (int u = 0; u < CH; ++u) {
    run = fmaxf(run, av[u]);
    size_t o = (size_t)bh * S_ + base + u;
    a_out[o] = av[u];
    amax_out[o] = run;
  }
}

// ---------------- barrier-free per-wave attention tile (16 rows) ----------------
__device__ __forceinline__ void attn_tile_proc(
    int t, int b, int h, int bh, int l15, int lg,
    const float* __restrict__ qin,
    const unsigned short* __restrict__ KsrcH, const unsigned short* __restrict__ KsrcL,
    const unsigned short* __restrict__ TsrcH, const unsigned short* __restrict__ TsrcL,
    const float* __restrict__ abase, const float* __restrict__ amax_arr,
    const float* __restrict__ lnw,
    float* __restrict__ out, unsigned short* __restrict__ outH,
    unsigned short* __restrict__ outL,
    int write_bf, int orow0, int out_srows,
    unsigned char* PwH, unsigned char* PwL) {
  int i0 = t * 16;
  // Q hi/lo fragments for row i0 + l15
  short8 qh[2], qlo[2];
  {
    const float* qrow = qin + ((size_t)(b * S_ + i0 + l15)) * D_ + h * DH_;
#pragma unroll
    for (int ks = 0; ks < 2; ++ks) {
      const float* p = qrow + ks * 32 + lg * 8;
      float4 v0 = *(const float4*)(p);
      float4 v1 = *(const float4*)(p + 4);
      float xv[8] = {v0.x, v0.y, v0.z, v0.w, v1.x, v1.y, v1.z, v1.w};
      unsigned short hh[8], ll[8];
#pragma unroll
      for (int k = 0; k < 8; ++k) {
        hh[k] = f2bf(xv[k]);
        ll[k] = f2bf(xv[k] - bf2f(hh[k]));
      }
      qh[ks] = *(const short8*)hh;
      qlo[ks] = *(const short8*)ll;
    }
  }
  float am_i = amax_arr[(size_t)bh * S_ + i0 + l15];
  int i_g = i0 + l15;
  f32x4 acc[4];
#pragma unroll
  for (int nt = 0; nt < 4; ++nt) acc[nt] = (f32x4){0.f, 0.f, 0.f, 0.f};

  int jt_max = (i0 + 15) >> 6;
  for (int jt = 0; jt <= jt_max; ++jt) {
    int j0 = jt * 64;
    // QK^T (swapped): st[r] = score(j = j0+js*16+lg*4+r, i = i0+l15)
#pragma unroll
    for (int js = 0; js < 4; ++js) {
      int jr = j0 + js * 16 + l15;
      const unsigned short* kp = KsrcH + (size_t)jr * 64 + lg * 8;
      const unsigned short* kpl = KsrcL + (size_t)jr * 64 + lg * 8;
      short8 kh0 = *(const short8*)(kp);
      short8 kh1 = *(const short8*)(kp + 32);
      short8 kl0 = *(const short8*)(kpl);
      short8 kl1 = *(const short8*)(kpl + 32);
      f32x4 st = (f32x4){0.f, 0.f, 0.f, 0.f};
      st = __builtin_amdgcn_mfma_f32_16x16x32_bf16(kh0, qh[0], st, 0, 0, 0);
      st = __builtin_amdgcn_mfma_f32_16x16x32_bf16(kh1, qh[1], st, 0, 0, 0);
      st = __builtin_amdgcn_mfma_f32_16x16x32_bf16(kh0, qlo[0], st, 0, 0, 0);
      st = __builtin_amdgcn_mfma_f32_16x16x32_bf16(kh1, qlo[1], st, 0, 0, 0);
      st = __builtin_amdgcn_mfma_f32_16x16x32_bf16(kl0, qh[0], st, 0, 0, 0);
      st = __builtin_amdgcn_mfma_f32_16x16x32_bf16(kl1, qh[1], st, 0, 0, 0);
      int jb = js * 16 + lg * 4;
      unsigned int pkh[2], pkl[2];
#pragma unroll
      for (int r2 = 0; r2 < 2; ++r2) {
        unsigned int ph = 0, pl = 0;
#pragma unroll
        for (int rr = 0; rr < 2; ++rr) {
          int r = r2 * 2 + rr;
          int jl = jb + r;
          float e = __expf(fminf(abase[j0 + jl] - am_i, 0.f));
          float wv = (j0 + jl <= i_g) ? st[r] * 0.125f * e : 0.f;
          unsigned short whi = f2bf(wv);
          ph |= (unsigned int)whi << (rr * 16);
          pl |= (unsigned int)f2bf(wv - bf2f(whi)) << (rr * 16);
        }
        pkh[r2] = ph; pkl[r2] = pl;
      }
      int g = js * 2 + (lg >> 1);
      int pw_off = l15 * 128 + ((g ^ (l15 & 7)) * 16) + (lg & 1) * 8;
      *(uint2*)(PwH + pw_off) = make_uint2(pkh[0], pkh[1]);
      *(uint2*)(PwL + pw_off) = make_uint2(pkl[0], pkl[1]);
    }
    // PV: acc[nt][r] += P[i0+lg*4+r][j] * V[j][nt*16+l15]
#pragma unroll
    for (int ks = 0; ks < 2; ++ks) {
      int pg = ((ks * 4 + lg) ^ (l15 & 7)) * 16;
      short8 ph = *(const short8*)(PwH + l15 * 128 + pg);
      short8 pl = *(const short8*)(PwL + l15 * 128 + pg);
#pragma unroll
      for (int nt = 0; nt < 4; ++nt) {
        const unsigned short* vp = TsrcH + (size_t)(nt * 16 + l15) * S_ + j0 + (ks * 4 + lg) * 8;
        const unsigned short* vpl = TsrcL + (size_t)(nt * 16 + l15) * S_ + j0 + (ks * 4 + lg) * 8;
        short8 vh = *(const short8*)vp;
        short8 vl = *(const short8*)vpl;
        acc[nt] = __builtin_amdgcn_mfma_f32_16x16x32_bf16(ph, vh, acc[nt], 0, 0, 0);
        acc[nt] = __builtin_amdgcn_mfma_f32_16x16x32_bf16(pl, vh, acc[nt], 0, 0, 0);
        acc[nt] = __builtin_amdgcn_mfma_f32_16x16x32_bf16(ph, vl, acc[nt], 0, 0, 0);
      }
    }
  }

  // epilogue: LN only (normalizer cancels under LN)
  float lw[4];
#pragma unroll
  for (int nt = 0; nt < 4; ++nt) lw[nt] = lnw[h * DH_ + nt * 16 + l15];
#pragma unroll
  for (int r = 0; r < 4; ++r) {
    int i_glob = i0 + lg * 4 + r;
    float hv[4], s1 = 0.f, s2 = 0.f;
#pragma unroll
    for (int nt = 0; nt < 4; ++nt) {
      hv[nt] = acc[nt][r];
      s1 += hv[nt]; s2 += hv[nt] * hv[nt];
    }
#pragma unroll
    for (int off = 1; off < 16; off <<= 1) {
      s1 += __shfl_xor(s1, off); s2 += __shfl_xor(s2, off);
    }
    float mean = s1 * (1.f / 64.f);
    float var = s2 * (1.f / 64.f) - mean * mean;
    float rstd = rsqrtf(var + 1e-5f);
    size_t ro = ((size_t)(b * out_srows + (i_glob - orow0))) * D_ + h * DH_;
    if (!write_bf) {
#pragma unroll
      for (int nt = 0; nt < 4; ++nt)
        out[ro + nt * 16 + l15] = (hv[nt] - mean) * rstd * lw[nt];
    } else {
#pragma unroll
      for (int nt = 0; nt < 4; ++nt) {
        float v = (hv[nt] - mean) * rstd * lw[nt];
        unsigned short hi = f2bf(v);
        outH[ro + nt * 16 + l15] = hi;
        outL[ro + nt * 16 + l15] = f2bf(v - bf2f(hi));
      }
    }
  }
}

// mode 0 (L1): grid (8,NH,B); wave pair (t, 63-t) => 17 units/wave, balanced.
// mode 1 (L2): grid (2,NH,B); wave handles tile 56+pi (rows 896..1023 only).
__global__ __launch_bounds__(256) void attn_wave_kernel(
    const float* __restrict__ qin,
    const unsigned short* __restrict__ kH, const unsigned short* __restrict__ kL,
    const unsigned short* __restrict__ tH, const unsigned short* __restrict__ tL,
    const float* __restrict__ a_arr, const float* __restrict__ amax_arr,
    const float* __restrict__ lnw, float* __restrict__ out,
    unsigned short* __restrict__ outH, unsigned short* __restrict__ outL,
    int write_bf, int mode, int orow0, int out_srows) {
  int tid = threadIdx.x;
  int w = tid >> 6, l = tid & 63;
  int l15 = l & 15, lg = l >> 4;
  __shared__ __align__(16) unsigned char smem[16384];
  unsigned char* PwH = smem + w * 4096;
  unsigned char* PwL = PwH + 2048;

  int b, h, pi;
  if (mode == 0) {
    // XCD-grouping swizzle: all 8 blocks of one (b,h) on one XCD
    int f = blockIdx.x + 8 * (blockIdx.y + 8 * blockIdx.z);  // 0..255
    int xcd = f & 7, s = f >> 3;                              // s: 0..31
    int bh = xcd * 4 + (s & 3);                               // 4 bh per xcd
    b = bh >> 3; h = bh & 7;
    pi = (s >> 2) * 4 + w;                                    // 0..31
  } else {
    int f = blockIdx.x + 2 * (blockIdx.y + 8 * blockIdx.z);   // 0..63
    int xcd = f & 7, s = f >> 3;                              // s: 0..7
    int bh = xcd * 4 + (s & 3);
    b = bh >> 3; h = bh & 7;
    pi = (s >> 2) * 4 + w;                                    // 0..7
  }
  int bh = b * NH_ + h;
  const unsigned short* KsrcH = kH + (size_t)bh * S_ * 64;
  const unsigned short* KsrcL = kL + (size_t)bh * S_ * 64;
  const unsigned short* TsrcH = tH + (size_t)bh * 64 * S_;
  const unsigned short* TsrcL = tL + (size_t)bh * 64 * S_;
  const float* abase = a_arr + (size_t)bh * S_;

  int tA = (mode == 0) ? pi : (56 + pi);
  attn_tile_proc(tA, b, h, bh, l15, lg, qin, KsrcH, KsrcL, TsrcH, TsrcL,
                 abase, amax_arr, lnw, out, outH, outL,
                 write_bf, orow0, out_srows, PwH, PwL);
  if (mode == 0) {
    attn_tile_proc(63 - pi, b, h, bh, l15, lg, qin, KsrcH, KsrcL, TsrcH, TsrcL,
                   abase, amax_arr, lnw, out, outH, outL,
                   write_bf, orow0, out_srows, PwH, PwL);
  }
}

// ---------------- final head via MFMA: out[384,512] = q2 . W^T + b ----------------
__global__ __launch_bounds__(256) void fc3_kernel(
    const unsigned short* __restrict__ qH, const unsigned short* __restrict__ qL,
    const float* __restrict__ W, const float* __restrict__ bias,
    float* __restrict__ out) {
  int rt = blockIdx.x, ot = blockIdx.y;
  int tid = threadIdx.x;
  int w = tid >> 6, l = tid & 63, l15 = l & 15, lg = l >> 4;
  int r_flat = rt * 64 + w * 16 + l15;
  int b = r_flat / 96, pc = r_flat - b * 96;
  const unsigned short* qHrow = qH + ((size_t)(b * 128 + 32 + pc)) * D_;
  const unsigned short* qLrow = qL + ((size_t)(b * 128 + 32 + pc)) * D_;
  int obase = ot * 64;

  f32x4 acc[4];
#pragma unroll
  for (int og = 0; og < 4; ++og) acc[og] = (f32x4){0.f, 0.f, 0.f, 0.f};

#pragma unroll 2
  for (int ks = 0; ks < 16; ++ks) {
    int k0 = ks * 32 + lg * 8;
    short8 ah = *(const short8*)(qHrow + k0);
    short8 al = *(const short8*)(qLrow + k0);
#pragma unroll
    for (int og = 0; og < 4; ++og) {
      const float* wrow = W + (size_t)(obase + og * 16 + l15) * D_ + k0;
      float4 w0 = *(const float4*)(wrow);
      float4 w1 = *(const float4*)(wrow + 4);
      float wv[8] = {w0.x, w0.y, w0.z, w0.w, w1.x, w1.y, w1.z, w1.w};
      unsigned short bhh[8], bll[8];
#pragma unroll
      for (int k = 0; k < 8; ++k) {
        bhh[k] = f2bf(wv[k]);
        bll[k] = f2bf(wv[k] - bf2f(bhh[k]));
      }
      short8 bh = *(const short8*)bhh;
      short8 bl = *(const short8*)bll;
      acc[og] = __builtin_amdgcn_mfma_f32_16x16x32_bf16(ah, bh, acc[og], 0, 0, 0);
      acc[og] = __builtin_amdgcn_mfma_f32_16x16x32_bf16(al, bh, acc[og], 0, 0, 0);
      acc[og] = __builtin_amdgcn_mfma_f32_16x16x32_bf16(ah, bl, acc[og], 0, 0, 0);
    }
  }
  int rbase = rt * 64 + w * 16 + lg * 4;
#pragma unroll
  for (int og = 0; og < 4; ++og) {
    int o = obase + og * 16 + l15;
    float bs = bias[o];
#pragma unroll
    for (int r = 0; r < 4; ++r)
      out[(size_t)(rbase + r) * COUT_ + o] = acc[og][r] + bs;
  }
}

extern "C" void kernel_launch(void* const* d_in, const int* in_sizes, int n_in,
                              void* d_out, int out_size, void* d_ws, size_t ws_size,
                              hipStream_t stream) {
  const float* x_enc = (const float*)d_in[0];
  const float* W_ig = (const float*)d_in[4];
  const float* b_ig = (const float*)d_in[5];
  const float* W_fg = (const float*)d_in[6];
  const float* b_fg = (const float*)d_in[7];
  const float* ln_w = (const float*)d_in[8];
  const float* fc_W = (const float*)d_in[9];
  const float* fc_b = (const float*)d_in[10];

  float* ws = (float*)d_ws;
  const size_t NBSD = (size_t)B_ * S_ * D_;   // 2,097,152
  const size_t NBHS = (size_t)B_ * NH_ * S_;  // 32,768
  float* h1 = ws;                      // [B,S,D] f32 (layer-1 output)
  float* ig = h1 + NBSD;
  float* fg = ig + NBHS;
  float* aA = fg + NBHS;
  float* amaxA = aA + NBHS;
  unsigned short* kvhH = (unsigned short*)(amaxA + NBHS);
  unsigned short* kvhL = kvhH + NBSD;
  unsigned short* kvTH = kvhL + NBSD;
  unsigned short* kvTL = kvTH + NBSD;
  unsigned short* hqH = kvTL + NBSD;   // [B,128,512] bf16 hi (layer-2 rows 896..1023)
  unsigned short* hqL = hqH + (size_t)B_ * 128 * D_;
  // total footprint: 26,738,688 bytes == proven layout

  convkv_kernel<<<B_ * S_, 64, 0, stream>>>(x_enc, kvhH, kvhL);
  transpose_kernel<<<dim3(S_ / 64, NH_, B_), 256, 0, stream>>>(kvhH, kvTH);
  transpose_kernel<<<dim3(S_ / 64, NH_, B_), 256, 0, stream>>>(kvhL, kvTL);

  for (int l = 0; l < L_; ++l) {
    const float* qin = (l == 0) ? x_enc : h1;
    gates2_kernel<<<dim3(S_ / 32, 2, B_), 256, 0, stream>>>(
        qin, x_enc,
        W_ig + (size_t)l * NH_ * 3 * D_, b_ig + (size_t)l * NH_,
        W_fg + (size_t)l * NH_ * 3 * D_, b_fg + (size_t)l * NH_, ig, fg);
    scan_kernel<<<B_ * NH_, 64, 0, stream>>>(ig, fg, aA, amaxA);
    if (l == 0) {
      attn_wave_kernel<<<dim3(8, NH_, B_), 256, 0, stream>>>(
          qin, kvhH, kvhL, kvTH, kvTL, aA, amaxA, ln_w + (size_t)l * D_,
          h1, (unsigned short*)nullptr, (unsigned short*)nullptr, 0, 0, 0, S_);
    } else {
      attn_wave_kernel<<<dim3(2, NH_, B_), 256, 0, stream>>>(
          qin, kvhH, kvhL, kvTH, kvTL, aA, amaxA, ln_w + (size_t)l * D_,
          (float*)nullptr, hqH, hqL, 1, 1, 896, 128);
    }
  }
  fc3_kernel<<<dim3(6, 8), 256, 0, stream>>>(hqH, hqL, fc_W, fc_b, (float*)d_out);
}

// Round 12
// 340.262 us; speedup vs baseline: 1.1244x; 1.1244x over previous
//
#include <hip/hip_runtime.h>
#include <hip/hip_bf16.h>
#include <math.h>
#include <stdint.h>

#define B_ 4
#define S_ 1024
#define D_ 512
#define NH_ 8
#define DH_ 64
#define L_ 2
#define PRED_ 96
#define COUT_ 512

typedef __attribute__((ext_vector_type(8))) short short8;
typedef __attribute__((ext_vector_type(4))) float f32x4;

__device__ __forceinline__ unsigned short f2bf(float f) {
  union { float f; unsigned int u; } v; v.f = f;
  unsigned int r = v.u + 0x7fffu + ((v.u >> 16) & 1u);
  return (unsigned short)(r >> 16);
}
__device__ __forceinline__ float bf2f(unsigned short h) {
  union { unsigned int u; float f; } v; v.u = (unsigned int)h << 16;
  return v.f;
}

// ---------------- x_enc f32 [B,S,512] -> hi/lo bf16 [B*NH, S, 64] ----------------
__global__ __launch_bounds__(64) void convkv_kernel(
    const float* __restrict__ x, unsigned short* __restrict__ hiA,
    unsigned short* __restrict__ loA) {
  int bs = blockIdx.x;
  int b = bs >> 10, s = bs & 1023;
  int t = threadIdx.x;
  int h = t >> 3, dh0 = (t & 7) * 8;
  const float* src = x + (size_t)bs * D_ + t * 8;
  float4 v0 = *(const float4*)(src);
  float4 v1 = *(const float4*)(src + 4);
  float xv[8] = {v0.x, v0.y, v0.z, v0.w, v1.x, v1.y, v1.z, v1.w};
  unsigned short hh[8], ll[8];
#pragma unroll
  for (int k = 0; k < 8; ++k) {
    hh[k] = f2bf(xv[k]);
    ll[k] = f2bf(xv[k] - bf2f(hh[k]));
  }
  size_t off = (((size_t)(b * NH_ + h)) * S_ + s) * 64 + dh0;
  *(uint4*)(hiA + off) = *(const uint4*)hh;
  *(uint4*)(loA + off) = *(const uint4*)ll;
}

// ---------------- [B*NH,S,64] -> [B*NH,64,S] ----------------
__global__ __launch_bounds__(256) void transpose_kernel(
    const unsigned short* __restrict__ src_a, unsigned short* __restrict__ dst_a) {
  int jt = blockIdx.x, h = blockIdx.y, b = blockIdx.z;
  int bh = b * NH_ + h, j0 = jt * 64;
  __shared__ unsigned short tile[64][72];
  int t = threadIdx.x;
  {
    int j = t >> 2, dseg = (t & 3) * 16;
    const unsigned short* src = src_a + ((size_t)bh * S_ + j0 + j) * 64 + dseg;
    uint4 a0 = *(const uint4*)(src);
    uint4 a1 = *(const uint4*)(src + 8);
    *(uint4*)(&tile[j][dseg]) = a0;
    *(uint4*)(&tile[j][dseg + 8]) = a1;
  }
  __syncthreads();
  {
    int d = t >> 2, jseg = (t & 3) * 16;
    unsigned short us[16];
#pragma unroll
    for (int k = 0; k < 16; ++k) us[k] = tile[jseg + k][d];
    unsigned short* dst = dst_a + ((size_t)bh * 64 + d) * S_ + j0 + jseg;
    *(uint4*)(dst) = *(const uint4*)us;
    *(uint4*)(dst + 8) = *(const uint4*)(us + 8);
  }
}

// ---------------- gates ----------------
__global__ __launch_bounds__(256) void gates2_kernel(
    const float* __restrict__ q, const float* __restrict__ x,
    const float* __restrict__ Wig, const float* __restrict__ big,
    const float* __restrict__ Wfg, const float* __restrict__ bfg,
    float* __restrict__ ig_out, float* __restrict__ fg_out) {
  int sc = blockIdx.x, hg = blockIdx.y, b = blockIdx.z;
  __shared__ float Wq_s[8][512];
  __shared__ float Wc_s[8][512];
  for (int idx = threadIdx.x; idx < 8 * 512; idx += 256) {
    int p = idx >> 9, e = idx & 511;
    int h = hg * 4 + (p >> 1);
    const float* Wr = ((p & 1) ? Wfg : Wig) + (size_t)h * (3 * D_);
    Wq_s[p][e] = Wr[e];
    Wc_s[p][e] = Wr[512 + e] + Wr[1024 + e];
  }
  __syncthreads();
  int wv = threadIdx.x >> 6, l = threadIdx.x & 63;
  for (int rr = 0; rr < 8; ++rr) {
    int s = sc * 32 + wv * 8 + rr;
    const float* qrow = q + ((size_t)(b * S_ + s)) * D_;
    const float* xrow = x + ((size_t)(b * S_ + s)) * D_;
    float ql[8], xl[8];
#pragma unroll
    for (int k = 0; k < 8; ++k) { ql[k] = qrow[l + 64 * k]; xl[k] = xrow[l + 64 * k]; }
#pragma unroll
    for (int p = 0; p < 8; ++p) {
      float acc = 0.f;
#pragma unroll
      for (int k = 0; k < 8; ++k)
        acc += Wq_s[p][l + 64 * k] * ql[k] + Wc_s[p][l + 64 * k] * xl[k];
#pragma unroll
      for (int off = 32; off; off >>= 1) acc += __shfl_down(acc, off);
      if (l == 0) {
        int h = hg * 4 + (p >> 1);
        float v = acc + ((p & 1) ? bfg : big)[h];
        ((p & 1) ? fg_out : ig_out)[((size_t)(b * NH_ + h)) * S_ + s] = v;
      }
    }
  }
}

// ---------------- scan: a = ig - cumsum(logsig(fg)); amax = cummax(a) ----------------
__global__ __launch_bounds__(64) void scan_kernel(
    const float* __restrict__ ig, const float* __restrict__ fg,
    float* __restrict__ a_out, float* __restrict__ amax_out) {
  int bh = blockIdx.x;
  int lane = threadIdx.x;
  const float* igr = ig + (size_t)bh * S_;
  const float* fgr = fg + (size_t)bh * S_;
  const int CH = S_ / 64;
  float lf[16], av[16];
  float lsum = 0.f;
  int base = lane * CH;
  for (int u = 0; u < CH; ++u) {
    float xv = fgr[base + u];
    float ls = (xv >= 0.f) ? -log1pf(__expf(-xv)) : (xv - log1pf(__expf(xv)));
    lf[u] = ls; lsum += ls;
  }
  float pref = lsum;
#pragma unroll
  for (int off = 1; off < 64; off <<= 1) {
    float t = __shfl_up(pref, off);
    if (lane >= off) pref += t;
  }
  float F = pref - lsum;
  float lamax = -INFINITY;
  for (int u = 0; u < CH; ++u) {
    F += lf[u];
    float a = igr[base + u] - F;
    av[u] = a;
    lamax = fmaxf(lamax, a);
  }
  float pmax = lamax;
#pragma unroll
  for (int off = 1; off < 64; off <<= 1) {
    float t = __shfl_up(pmax, off);
    if (lane >= off) pmax = fmaxf(pmax, t);
  }
  float run = __shfl_up(pmax, 1);
  if (lane == 0) run = -INFINITY;
  for (int u = 0; u < CH; ++u) {
    run = fmaxf(run, av[u]);
    size_t o = (size_t)bh * S_ + base + u;
    a_out[o] = av[u];
    amax_out[o] = run;
  }
}

// ---------------- barrier-free per-wave attention tile (16 rows), reg-prefetch ----------------
__device__ __forceinline__ void attn_tile_proc(
    int t, int b, int h, int bh, int l15, int lg,
    const float* __restrict__ qin,
    const unsigned short* __restrict__ KsrcH, const unsigned short* __restrict__ KsrcL,
    const unsigned short* __restrict__ TsrcH, const unsigned short* __restrict__ TsrcL,
    const float* __restrict__ abase, const float* __restrict__ amax_arr,
    const float* __restrict__ lnw,
    float* __restrict__ out, unsigned short* __restrict__ outH,
    unsigned short* __restrict__ outL,
    int write_bf, int orow0, int out_srows,
    unsigned char* PwH, unsigned char* PwL) {
  int i0 = t * 16;
  // Q hi/lo fragments for row i0 + l15
  short8 qh[2], qlo[2];
  {
    const float* qrow = qin + ((size_t)(b * S_ + i0 + l15)) * D_ + h * DH_;
#pragma unroll
    for (int ks = 0; ks < 2; ++ks) {
      const float* p = qrow + ks * 32 + lg * 8;
      float4 v0 = *(const float4*)(p);
      float4 v1 = *(const float4*)(p + 4);
      float xv[8] = {v0.x, v0.y, v0.z, v0.w, v1.x, v1.y, v1.z, v1.w};
      unsigned short hh[8], ll[8];
#pragma unroll
      for (int k = 0; k < 8; ++k) {
        hh[k] = f2bf(xv[k]);
        ll[k] = f2bf(xv[k] - bf2f(hh[k]));
      }
      qh[ks] = *(const short8*)hh;
      qlo[ks] = *(const short8*)ll;
    }
  }
  float am_i = amax_arr[(size_t)bh * S_ + i0 + l15];
  int i_g = i0 + l15;
  f32x4 acc[4];
#pragma unroll
  for (int nt = 0; nt < 4; ++nt) acc[nt] = (f32x4){0.f, 0.f, 0.f, 0.f};

  int jt_max = (i0 + 15) >> 6;
  for (int jt = 0; jt <= jt_max; ++jt) {
    int j0 = jt * 64;
    // ---- prefetch: ALL operands of this j-tile into registers (one latency wall) ----
    short8 kh0a[4], kh1a[4], kl0a[4], kl1a[4];
    float4 ea[4];
#pragma unroll
    for (int js = 0; js < 4; ++js) {
      int jr = j0 + js * 16 + l15;
      const unsigned short* kp = KsrcH + (size_t)jr * 64 + lg * 8;
      const unsigned short* kpl = KsrcL + (size_t)jr * 64 + lg * 8;
      kh0a[js] = *(const short8*)(kp);
      kh1a[js] = *(const short8*)(kp + 32);
      kl0a[js] = *(const short8*)(kpl);
      kl1a[js] = *(const short8*)(kpl + 32);
      ea[js] = *(const float4*)(abase + j0 + js * 16 + lg * 4);
    }
    short8 vha[2][4], vla[2][4];
#pragma unroll
    for (int ks = 0; ks < 2; ++ks)
#pragma unroll
      for (int nt = 0; nt < 4; ++nt) {
        const unsigned short* vp = TsrcH + (size_t)(nt * 16 + l15) * S_ + j0 + (ks * 4 + lg) * 8;
        const unsigned short* vpl = TsrcL + (size_t)(nt * 16 + l15) * S_ + j0 + (ks * 4 + lg) * 8;
        vha[ks][nt] = *(const short8*)vp;
        vla[ks][nt] = *(const short8*)vpl;
      }
    // ---- QK^T (swapped), 3 independent 2-chains, weight + pack ----
#pragma unroll
    for (int js = 0; js < 4; ++js) {
      f32x4 sa = (f32x4){0.f, 0.f, 0.f, 0.f};
      f32x4 sb = (f32x4){0.f, 0.f, 0.f, 0.f};
      f32x4 sc = (f32x4){0.f, 0.f, 0.f, 0.f};
      sa = __builtin_amdgcn_mfma_f32_16x16x32_bf16(kh0a[js], qh[0], sa, 0, 0, 0);
      sa = __builtin_amdgcn_mfma_f32_16x16x32_bf16(kh1a[js], qh[1], sa, 0, 0, 0);
      sb = __builtin_amdgcn_mfma_f32_16x16x32_bf16(kh0a[js], qlo[0], sb, 0, 0, 0);
      sb = __builtin_amdgcn_mfma_f32_16x16x32_bf16(kh1a[js], qlo[1], sb, 0, 0, 0);
      sc = __builtin_amdgcn_mfma_f32_16x16x32_bf16(kl0a[js], qh[0], sc, 0, 0, 0);
      sc = __builtin_amdgcn_mfma_f32_16x16x32_bf16(kl1a[js], qh[1], sc, 0, 0, 0);
      f32x4 st = sa + sb + sc;
      int jb = js * 16 + lg * 4;
      unsigned int pkh[2], pkl[2];
#pragma unroll
      for (int r2 = 0; r2 < 2; ++r2) {
        unsigned int ph = 0, pl = 0;
#pragma unroll
        for (int rr = 0; rr < 2; ++rr) {
          int r = r2 * 2 + rr;
          int jl = jb + r;
          float e = __expf(fminf(ea[js][r] - am_i, 0.f));
          float wv = (j0 + jl <= i_g) ? st[r] * 0.125f * e : 0.f;
          unsigned short whi = f2bf(wv);
          ph |= (unsigned int)whi << (rr * 16);
          pl |= (unsigned int)f2bf(wv - bf2f(whi)) << (rr * 16);
        }
        pkh[r2] = ph; pkl[r2] = pl;
      }
      int g = js * 2 + (lg >> 1);
      int pw_off = l15 * 128 + ((g ^ (l15 & 7)) * 16) + (lg & 1) * 8;
      *(uint2*)(PwH + pw_off) = make_uint2(pkh[0], pkh[1]);
      *(uint2*)(PwL + pw_off) = make_uint2(pkl[0], pkl[1]);
    }
    // ---- PV: acc[nt][r] += P[i0+lg*4+r][j] * V[j][nt*16+l15] ----
#pragma unroll
    for (int ks = 0; ks < 2; ++ks) {
      int pg = ((ks * 4 + lg) ^ (l15 & 7)) * 16;
      short8 ph = *(const short8*)(PwH + l15 * 128 + pg);
      short8 pl = *(const short8*)(PwL + l15 * 128 + pg);
#pragma unroll
      for (int nt = 0; nt < 4; ++nt) {
        acc[nt] = __builtin_amdgcn_mfma_f32_16x16x32_bf16(ph, vha[ks][nt], acc[nt], 0, 0, 0);
        acc[nt] = __builtin_amdgcn_mfma_f32_16x16x32_bf16(pl, vha[ks][nt], acc[nt], 0, 0, 0);
        acc[nt] = __builtin_amdgcn_mfma_f32_16x16x32_bf16(ph, vla[ks][nt], acc[nt], 0, 0, 0);
      }
    }
  }

  // epilogue: LN only (normalizer cancels under LN)
  float lw[4];
#pragma unroll
  for (int nt = 0; nt < 4; ++nt) lw[nt] = lnw[h * DH_ + nt * 16 + l15];
#pragma unroll
  for (int r = 0; r < 4; ++r) {
    int i_glob = i0 + lg * 4 + r;
    float hv[4], s1 = 0.f, s2 = 0.f;
#pragma unroll
    for (int nt = 0; nt < 4; ++nt) {
      hv[nt] = acc[nt][r];
      s1 += hv[nt]; s2 += hv[nt] * hv[nt];
    }
#pragma unroll
    for (int off = 1; off < 16; off <<= 1) {
      s1 += __shfl_xor(s1, off); s2 += __shfl_xor(s2, off);
    }
    float mean = s1 * (1.f / 64.f);
    float var = s2 * (1.f / 64.f) - mean * mean;
    float rstd = rsqrtf(var + 1e-5f);
    size_t ro = ((size_t)(b * out_srows + (i_glob - orow0))) * D_ + h * DH_;
    if (!write_bf) {
#pragma unroll
      for (int nt = 0; nt < 4; ++nt)
        out[ro + nt * 16 + l15] = (hv[nt] - mean) * rstd * lw[nt];
    } else {
#pragma unroll
      for (int nt = 0; nt < 4; ++nt) {
        float v = (hv[nt] - mean) * rstd * lw[nt];
        unsigned short hi = f2bf(v);
        outH[ro + nt * 16 + l15] = hi;
        outL[ro + nt * 16 + l15] = f2bf(v - bf2f(hi));
      }
    }
  }
}

// mode 0 (L1): 512 blocks, 1 tile per wave (2048 waves, 2/SIMD).
//   block u=f>>3, g=u>>2: tiles {g, 31-g, 32+g, 63-g}; flip by (g>>3)&1 for SIMD balance.
// mode 1 (L2): 64 blocks; wave handles tile 56 + half*4 + w (rows 896..1023 only).
__global__ __launch_bounds__(256, 2) void attn_wave_kernel(
    const float* __restrict__ qin,
    const unsigned short* __restrict__ kH, const unsigned short* __restrict__ kL,
    const unsigned short* __restrict__ tH, const unsigned short* __restrict__ tL,
    const float* __restrict__ a_arr, const float* __restrict__ amax_arr,
    const float* __restrict__ lnw, float* __restrict__ out,
    unsigned short* __restrict__ outH, unsigned short* __restrict__ outL,
    int write_bf, int mode, int orow0, int out_srows) {
  int tid = threadIdx.x;
  int w = tid >> 6, l = tid & 63;
  int l15 = l & 15, lg = l >> 4;
  __shared__ __align__(16) unsigned char smem[16384];
  unsigned char* PwH = smem + w * 4096;
  unsigned char* PwL = PwH + 2048;

  int f = blockIdx.x;
  int xcd = f & 7, u = f >> 3;
  int b, h, tA;
  if (mode == 0) {
    int bh0 = xcd * 4 + (u & 3);
    b = bh0 >> 3; h = bh0 & 7;
    int g = u >> 2;                       // 0..15
    int flip = (g >> 3) & 1;
    int idx = flip ? (3 - w) : w;
    int hi2 = idx >> 1, lo2 = idx & 1;
    tA = hi2 * 32 + (lo2 ? (31 - g) : g); // {g, 31-g, 32+g, 63-g}
  } else {
    int bh0 = xcd * 4 + (u & 3);
    b = bh0 >> 3; h = bh0 & 7;
    int half = u >> 2;                    // 0..1
    tA = 56 + half * 4 + w;               // 56..63
  }
  int bh = b * NH_ + h;
  const unsigned short* KsrcH = kH + (size_t)bh * S_ * 64;
  const unsigned short* KsrcL = kL + (size_t)bh * S_ * 64;
  const unsigned short* TsrcH = tH + (size_t)bh * 64 * S_;
  const unsigned short* TsrcL = tL + (size_t)bh * 64 * S_;
  const float* abase = a_arr + (size_t)bh * S_;

  attn_tile_proc(tA, b, h, bh, l15, lg, qin, KsrcH, KsrcL, TsrcH, TsrcL,
                 abase, amax_arr, lnw, out, outH, outL,
                 write_bf, orow0, out_srows, PwH, PwL);
}

// ---------------- final head via MFMA: out[384,512] = q2 . W^T + b ----------------
__global__ __launch_bounds__(256) void fc3_kernel(
    const unsigned short* __restrict__ qH, const unsigned short* __restrict__ qL,
    const float* __restrict__ W, const float* __restrict__ bias,
    float* __restrict__ out) {
  int rt = blockIdx.x, ot = blockIdx.y;
  int tid = threadIdx.x;
  int w = tid >> 6, l = tid & 63, l15 = l & 15, lg = l >> 4;
  int r_flat = rt * 64 + w * 16 + l15;
  int b = r_flat / 96, pc = r_flat - b * 96;
  const unsigned short* qHrow = qH + ((size_t)(b * 128 + 32 + pc)) * D_;
  const unsigned short* qLrow = qL + ((size_t)(b * 128 + 32 + pc)) * D_;
  int obase = ot * 64;

  f32x4 acc[4];
#pragma unroll
  for (int og = 0; og < 4; ++og) acc[og] = (f32x4){0.f, 0.f, 0.f, 0.f};

#pragma unroll 2
  for (int ks = 0; ks < 16; ++ks) {
    int k0 = ks * 32 + lg * 8;
    short8 ah = *(const short8*)(qHrow + k0);
    short8 al = *(const short8*)(qLrow + k0);
#pragma unroll
    for (int og = 0; og < 4; ++og) {
      const float* wrow = W + (size_t)(obase + og * 16 + l15) * D_ + k0;
      float4 w0 = *(const float4*)(wrow);
      float4 w1 = *(const float4*)(wrow + 4);
      float wv[8] = {w0.x, w0.y, w0.z, w0.w, w1.x, w1.y, w1.z, w1.w};
      unsigned short bhh[8], bll[8];
#pragma unroll
      for (int k = 0; k < 8; ++k) {
        bhh[k] = f2bf(wv[k]);
        bll[k] = f2bf(wv[k] - bf2f(bhh[k]));
      }
      short8 bh = *(const short8*)bhh;
      short8 bl = *(const short8*)bll;
      acc[og] = __builtin_amdgcn_mfma_f32_16x16x32_bf16(ah, bh, acc[og], 0, 0, 0);
      acc[og] = __builtin_amdgcn_mfma_f32_16x16x32_bf16(al, bh, acc[og], 0, 0, 0);
      acc[og] = __builtin_amdgcn_mfma_f32_16x16x32_bf16(ah, bl, acc[og], 0, 0, 0);
    }
  }
  int rbase = rt * 64 + w * 16 + lg * 4;
#pragma unroll
  for (int og = 0; og < 4; ++og) {
    int o = obase + og * 16 + l15;
    float bs = bias[o];
#pragma unroll
    for (int r = 0; r < 4; ++r)
      out[(size_t)(rbase + r) * COUT_ + o] = acc[og][r] + bs;
  }
}

extern "C" void kernel_launch(void* const* d_in, const int* in_sizes, int n_in,
                              void* d_out, int out_size, void* d_ws, size_t ws_size,
                              hipStream_t stream) {
  const float* x_enc = (const float*)d_in[0];
  const float* W_ig = (const float*)d_in[4];
  const float* b_ig = (const float*)d_in[5];
  const float* W_fg = (const float*)d_in[6];
  const float* b_fg = (const float*)d_in[7];
  const float* ln_w = (const float*)d_in[8];
  const float* fc_W = (const float*)d_in[9];
  const float* fc_b = (const float*)d_in[10];

  float* ws = (float*)d_ws;
  const size_t NBSD = (size_t)B_ * S_ * D_;   // 2,097,152
  const size_t NBHS = (size_t)B_ * NH_ * S_;  // 32,768
  float* h1 = ws;                      // [B,S,D] f32 (layer-1 output)
  float* ig = h1 + NBSD;
  float* fg = ig + NBHS;
  float* aA = fg + NBHS;
  float* amaxA = aA + NBHS;
  unsigned short* kvhH = (unsigned short*)(amaxA + NBHS);
  unsigned short* kvhL = kvhH + NBSD;
  unsigned short* kvTH = kvhL + NBSD;
  unsigned short* kvTL = kvTH + NBSD;
  unsigned short* hqH = kvTL + NBSD;   // [B,128,512] bf16 hi (layer-2 rows 896..1023)
  unsigned short* hqL = hqH + (size_t)B_ * 128 * D_;
  // total footprint: 26,738,688 bytes == proven layout

  convkv_kernel<<<B_ * S_, 64, 0, stream>>>(x_enc, kvhH, kvhL);
  transpose_kernel<<<dim3(S_ / 64, NH_, B_), 256, 0, stream>>>(kvhH, kvTH);
  transpose_kernel<<<dim3(S_ / 64, NH_, B_), 256, 0, stream>>>(kvhL, kvTL);

  for (int l = 0; l < L_; ++l) {
    const float* qin = (l == 0) ? x_enc : h1;
    gates2_kernel<<<dim3(S_ / 32, 2, B_), 256, 0, stream>>>(
        qin, x_enc,
        W_ig + (size_t)l * NH_ * 3 * D_, b_ig + (size_t)l * NH_,
        W_fg + (size_t)l * NH_ * 3 * D_, b_fg + (size_t)l * NH_, ig, fg);
    scan_kernel<<<B_ * NH_, 64, 0, stream>>>(ig, fg, aA, amaxA);
    if (l == 0) {
      attn_wave_kernel<<<512, 256, 0, stream>>>(
          qin, kvhH, kvhL, kvTH, kvTL, aA, amaxA, ln_w + (size_t)l * D_,
          h1, (unsigned short*)nullptr, (unsigned short*)nullptr, 0, 0, 0, S_);
    } else {
      attn_wave_kernel<<<64, 256, 0, stream>>>(
          qin, kvhH, kvhL, kvTH, kvTL, aA, amaxA, ln_w + (size_t)l * D_,
          (float*)nullptr, hqH, hqL, 1, 1, 896, 128);
    }
  }
  fc3_kernel<<<dim3(6, 8), 256, 0, stream>>>(hqH, hqL, fc_W, fc_b, (float*)d_out);
}